// Round 1
// baseline (34092.245 us; speedup 1.0000x reference)
//
#include <hip/hip_runtime.h>
#include <stdint.h>

typedef __attribute__((ext_vector_type(4))) float f32x4;
typedef __attribute__((ext_vector_type(8))) short s8v;
typedef __attribute__((ext_vector_type(4))) unsigned short u4v;
typedef __bf16 bf16x8 __attribute__((ext_vector_type(8)));

#define DEV static __device__ __forceinline__

constexpr int Bb = 2, Tt = 2048, DE = 1024, Hh = 2048, NH = 16, KD = 128, VD = 128, Vv = 32000;
constexpr int QKVC = NH * (2 * KD + VD);   // 6144
constexpr int NWG  = 64;                   // scan workgroups

DEV unsigned short f2bf(float x) {
    unsigned u = __builtin_bit_cast(unsigned, x);
    unsigned r = (u + 0x7fffu + ((u >> 16) & 1u)) >> 16;
    return (unsigned short)r;
}
DEV float bf2f(unsigned short b) {
    unsigned u = ((unsigned)b) << 16;
    return __builtin_bit_cast(float, u);
}
DEV bf16x8 as_bf(s8v v) { return __builtin_bit_cast(bf16x8, v); }

DEV void gll16(const void* g, void* l) {
    __builtin_amdgcn_global_load_lds((__attribute__((address_space(1))) void*)g,
                                     (__attribute__((address_space(3))) void*)l, 16, 0, 0);
}

// ---------------- fp32 -> bf16 convert ----------------
__global__ void k_cvt(const float* __restrict__ in, unsigned short* __restrict__ out, int n4) {
    int i = blockIdx.x * blockDim.x + threadIdx.x;
    if (i < n4) {
        float4 v = reinterpret_cast<const float4*>(in)[i];
        u4v o = {f2bf(v.x), f2bf(v.y), f2bf(v.z), f2bf(v.w)};
        reinterpret_cast<u4v*>(out)[i] = o;
    }
}

// ---------------- embedding gather + convert ----------------
__global__ void k_embed(const int* __restrict__ tok, const float* __restrict__ E,
                        unsigned short* __restrict__ x) {
    int bt = blockIdx.x;
    int t4 = threadIdx.x;   // 256 threads * 4 floats = 1024 = DE
    float4 v = reinterpret_cast<const float4*>(E + (size_t)tok[bt] * DE)[t4];
    u4v o = {f2bf(v.x), f2bf(v.y), f2bf(v.z), f2bf(v.w)};
    reinterpret_cast<u4v*>(x + (size_t)bt * DE)[t4] = o;
}

// ---------------- bf16 GEMM: C(MxN) = A(MxK) * Bw(NxK)^T + bias ----------------
template<int OUT_F32, int HAS_BIAS>
__global__ __launch_bounds__(256)
void k_gemm(const unsigned short* __restrict__ A, const unsigned short* __restrict__ Bw,
            const float* __restrict__ bias, void* __restrict__ Cv,
            int M, int N, int K) {
    __shared__ unsigned short As[128 * 32];
    __shared__ unsigned short Bs[128 * 32];
    const int tid = threadIdx.x;
    const int lane = tid & 63, wave = tid >> 6;
    const int wr = wave >> 1, wc = wave & 1;
    const int l15 = lane & 15, l16 = lane >> 4;
    const int m0 = blockIdx.y * 128, n0 = blockIdx.x * 128;

    f32x4 acc[4][4] = {};

    const int srow = tid >> 2, schunk = tid & 3;
    const unsigned short* gA = A + (size_t)(m0 + srow) * K + schunk * 8;
    const unsigned short* gB = Bw + (size_t)(n0 + srow) * K + schunk * 8;
    unsigned short* ldsA0 = As + wave * 512;
    unsigned short* ldsA1 = As + 2048 + wave * 512;
    unsigned short* ldsB0 = Bs + wave * 512;
    unsigned short* ldsB1 = Bs + 2048 + wave * 512;
    const size_t rs64 = (size_t)64 * K;

    for (int kt = 0; kt < K; kt += 32) {
        gll16(gA + kt, ldsA0);
        gll16(gA + rs64 + kt, ldsA1);
        gll16(gB + kt, ldsB0);
        gll16(gB + rs64 + kt, ldsB1);
        __syncthreads();
        s8v af[4], bfv[4];
        #pragma unroll
        for (int m = 0; m < 4; ++m)
            af[m] = *reinterpret_cast<const s8v*>(As + (wr * 64 + m * 16 + l15) * 32 + l16 * 8);
        #pragma unroll
        for (int n = 0; n < 4; ++n)
            bfv[n] = *reinterpret_cast<const s8v*>(Bs + (wc * 64 + n * 16 + l15) * 32 + l16 * 8);
        #pragma unroll
        for (int m = 0; m < 4; ++m)
            #pragma unroll
            for (int n = 0; n < 4; ++n)
                acc[m][n] = __builtin_amdgcn_mfma_f32_16x16x32_bf16(as_bf(af[m]), as_bf(bfv[n]), acc[m][n], 0, 0, 0);
        __syncthreads();
    }

    #pragma unroll
    for (int m = 0; m < 4; ++m) {
        const int r0 = m0 + wr * 64 + m * 16 + l16 * 4;
        #pragma unroll
        for (int n = 0; n < 4; ++n) {
            const int c = n0 + wc * 64 + n * 16 + l15;
            const float bv = HAS_BIAS ? bias[c] : 0.0f;
            #pragma unroll
            for (int j = 0; j < 4; ++j) {
                float v = acc[m][n][j] + bv;
                if (OUT_F32) ((float*)Cv)[(size_t)(r0 + j) * N + c] = v;
                else ((unsigned short*)Cv)[(size_t)(r0 + j) * N + c] = f2bf(v);
            }
        }
    }
}

// ---------------- persistent RNN scan ----------------
// h_t = gelu(xi_t + Wh h_{t-1});  64 WGs x 512 thr; each WG owns 32 columns.
__global__ __launch_bounds__(512)
void k_scan(const float* __restrict__ Wh, const float* __restrict__ xi,
            unsigned short* __restrict__ hs, float* __restrict__ hbuf,
            int* __restrict__ flags) {
    const int wg = blockIdx.x;
    const int tid = threadIdx.x;
    const int lane = tid & 63, wave = tid >> 6;
    const int j = tid >> 4;    // 0..31 column within slice
    const int kp = tid & 15;   // k partition
    const int jg = wg * 32 + j;

    __shared__ float hsh[2 * Hh];   // [b][k] fp32, 16KB

    // weights in VGPRs: w[q*4+i] = Wh[jg][kp*4 + q*64 + i]
    float w[128];
    const float* wrow = Wh + (size_t)jg * Hh;
    #pragma unroll
    for (int q = 0; q < 32; ++q) {
        float4 v = *reinterpret_cast<const float4*>(wrow + kp * 4 + q * 64);
        w[q * 4 + 0] = v.x; w[q * 4 + 1] = v.y; w[q * 4 + 2] = v.z; w[q * 4 + 3] = v.w;
    }
    for (int i = tid; i < 2 * Hh; i += 512) hsh[i] = 0.0f;
    __syncthreads();

    for (int t = 0; t < Tt; ++t) {
        float s0 = 0.f, s1 = 0.f;
        #pragma unroll
        for (int q = 0; q < 32; ++q) {
            float4 h0 = *reinterpret_cast<const float4*>(&hsh[kp * 4 + q * 64]);
            float4 h1 = *reinterpret_cast<const float4*>(&hsh[Hh + kp * 4 + q * 64]);
            s0 += w[q*4]*h0.x + w[q*4+1]*h0.y + w[q*4+2]*h0.z + w[q*4+3]*h0.w;
            s1 += w[q*4]*h1.x + w[q*4+1]*h1.y + w[q*4+2]*h1.z + w[q*4+3]*h1.w;
        }
        #pragma unroll
        for (int d = 8; d >= 1; d >>= 1) {
            s0 += __shfl_xor(s0, d);
            s1 += __shfl_xor(s1, d);
        }
        if (kp == 0) {
            float x0 = xi[(size_t)t * Hh + jg];
            float x1 = xi[(size_t)(Tt + t) * Hh + jg];
            float a0 = x0 + s0, a1 = x1 + s1;
            float h0 = 0.5f * a0 * (1.0f + erff(a0 * 0.70710678118654752f));
            float h1 = 0.5f * a1 * (1.0f + erff(a1 * 0.70710678118654752f));
            float* hd = hbuf + ((t + 1) & 1) * (2 * Hh);
            __hip_atomic_store(hd + jg,      h0, __ATOMIC_RELAXED, __HIP_MEMORY_SCOPE_AGENT);
            __hip_atomic_store(hd + Hh + jg, h1, __ATOMIC_RELAXED, __HIP_MEMORY_SCOPE_AGENT);
            hs[(size_t)t * Hh + jg]        = f2bf(h0);
            hs[(size_t)(Tt + t) * Hh + jg] = f2bf(h1);
        }
        __threadfence();
        __syncthreads();
        if (tid == 0)
            __hip_atomic_store(&flags[wg], t + 1, __ATOMIC_RELEASE, __HIP_MEMORY_SCOPE_AGENT);
        if (t + 1 < Tt) {
            if (wave == 0) {
                int spins = 0;
                for (;;) {
                    int v = __hip_atomic_load(&flags[lane], __ATOMIC_ACQUIRE, __HIP_MEMORY_SCOPE_AGENT);
                    if (__all(v >= t + 1)) break;
                    __builtin_amdgcn_s_sleep(2);
                    if (++spins > (1 << 22)) break;   // anti-hang insurance
                }
            }
            __syncthreads();
            const float* hsrc = hbuf + ((t + 1) & 1) * (2 * Hh);
            for (int i = tid; i < 2 * Hh; i += 512)
                hsh[i] = __hip_atomic_load(hsrc + i, __ATOMIC_RELAXED, __HIP_MEMORY_SCOPE_AGENT);
            __syncthreads();
        }
    }
}

// ---------------- causal flash attention ----------------
__global__ __launch_bounds__(256)
void k_attn(const unsigned short* __restrict__ qkv, unsigned short* __restrict__ ao) {
    const int tid = threadIdx.x;
    const int lane = tid & 63, wave = tid >> 6;
    const int l15 = lane & 15, l16 = lane >> 4;
    const int qt = blockIdx.x, bh = blockIdx.y;
    const int b = bh >> 4, hh = bh & 15;

    __shared__ unsigned short Ks[64][136];
    __shared__ unsigned short Vt[128][72];
    __shared__ unsigned short Ps[4][16][72];

    const int qr0 = qt * 64 + wave * 16;
    const unsigned short* qbase = qkv + (size_t)(b * Tt + qr0 + l15) * QKVC + hh * KD;
    s8v qf[4];
    #pragma unroll
    for (int kc = 0; kc < 4; ++kc)
        qf[kc] = *reinterpret_cast<const s8v*>(qbase + kc * 32 + l16 * 8);

    f32x4 o[8] = {};
    float mrow[4] = {-3e38f, -3e38f, -3e38f, -3e38f};
    float lrow[4] = {0.f, 0.f, 0.f, 0.f};

    const int kvend = qt * 64 + 64;
    for (int kv0 = 0; kv0 < kvend; kv0 += 64) {
        __syncthreads();
        {
            const int r = tid >> 4, c = tid & 15;
            #pragma unroll
            for (int p = 0; p < 4; ++p) {
                int row = r + p * 16;
                const unsigned short* src = qkv + (size_t)(b * Tt + kv0 + row) * QKVC + hh * KD;
                s8v kv8 = *reinterpret_cast<const s8v*>(src + NH * KD + c * 8);
                *reinterpret_cast<s8v*>(&Ks[row][c * 8]) = kv8;
                s8v vv8 = *reinterpret_cast<const s8v*>(src + 2 * NH * KD + c * 8);
                #pragma unroll
                for (int i = 0; i < 8; ++i)
                    Vt[c * 8 + i][row] = (unsigned short)vv8[i];
            }
        }
        __syncthreads();
        f32x4 s[4] = {};
        #pragma unroll
        for (int kc = 0; kc < 4; ++kc) {
            #pragma unroll
            for (int nf = 0; nf < 4; ++nf) {
                s8v kf = *reinterpret_cast<const s8v*>(&Ks[nf * 16 + l15][kc * 32 + l16 * 8]);
                s[nf] = __builtin_amdgcn_mfma_f32_16x16x32_bf16(as_bf(qf[kc]), as_bf(kf), s[nf], 0, 0, 0);
            }
        }
        const float sc = 0.088388347648318447f;   // 1/sqrt(128)
        #pragma unroll
        for (int nf = 0; nf < 4; ++nf)
            #pragma unroll
            for (int jj = 0; jj < 4; ++jj) {
                int col = kv0 + nf * 16 + l15;
                int row = qr0 + l16 * 4 + jj;
                s[nf][jj] = (col <= row) ? s[nf][jj] * sc : -3e38f;
            }
        #pragma unroll
        for (int jj = 0; jj < 4; ++jj) {
            float vm = fmaxf(fmaxf(s[0][jj], s[1][jj]), fmaxf(s[2][jj], s[3][jj]));
            vm = fmaxf(vm, __shfl_xor(vm, 1));
            vm = fmaxf(vm, __shfl_xor(vm, 2));
            vm = fmaxf(vm, __shfl_xor(vm, 4));
            vm = fmaxf(vm, __shfl_xor(vm, 8));
            float mn = fmaxf(mrow[jj], vm);
            float scale = __expf(mrow[jj] - mn);
            float ps = 0.f;
            #pragma unroll
            for (int nf = 0; nf < 4; ++nf) {
                float p = __expf(s[nf][jj] - mn);
                s[nf][jj] = p;
                ps += p;
            }
            ps += __shfl_xor(ps, 1); ps += __shfl_xor(ps, 2);
            ps += __shfl_xor(ps, 4); ps += __shfl_xor(ps, 8);
            lrow[jj] = lrow[jj] * scale + ps;
            mrow[jj] = mn;
            #pragma unroll
            for (int nf = 0; nf < 8; ++nf) o[nf][jj] *= scale;
        }
        #pragma unroll
        for (int nf = 0; nf < 4; ++nf)
            #pragma unroll
            for (int jj = 0; jj < 4; ++jj)
                Ps[wave][l16 * 4 + jj][nf * 16 + l15] = f2bf(s[nf][jj]);
        __syncthreads();
        #pragma unroll
        for (int kc = 0; kc < 2; ++kc) {
            s8v pf = *reinterpret_cast<const s8v*>(&Ps[wave][l15][kc * 32 + l16 * 8]);
            #pragma unroll
            for (int nf = 0; nf < 8; ++nf) {
                s8v vf = *reinterpret_cast<const s8v*>(&Vt[nf * 16 + l15][kc * 32 + l16 * 8]);
                o[nf] = __builtin_amdgcn_mfma_f32_16x16x32_bf16(as_bf(pf), as_bf(vf), o[nf], 0, 0, 0);
            }
        }
    }
    #pragma unroll
    for (int nf = 0; nf < 8; ++nf)
        #pragma unroll
        for (int jj = 0; jj < 4; ++jj) {
            float v = o[nf][jj] / lrow[jj];
            ao[(size_t)(b * Tt + qr0 + l16 * 4 + jj) * Hh + hh * VD + nf * 16 + l15] = f2bf(v);
        }
}

// ---------------- residual + LayerNorm ----------------
__global__ __launch_bounds__(256)
void k_ln(const unsigned short* __restrict__ aop, const unsigned short* __restrict__ rnn,
          const float* __restrict__ g, const float* __restrict__ be,
          unsigned short* __restrict__ y) {
    const int row = blockIdx.x, tid = threadIdx.x;
    const int lane = tid & 63, wave = tid >> 6;
    const size_t base = (size_t)row * Hh;
    s8v a8 = *reinterpret_cast<const s8v*>(aop + base + tid * 8);
    s8v r8 = *reinterpret_cast<const s8v*>(rnn + base + tid * 8);
    float v[8]; float s = 0.f;
    #pragma unroll
    for (int i = 0; i < 8; ++i) {
        v[i] = bf2f((unsigned short)a8[i]) + bf2f((unsigned short)r8[i]);
        s += v[i];
    }
    #pragma unroll
    for (int d = 32; d >= 1; d >>= 1) s += __shfl_xor(s, d);
    __shared__ float red[8];
    if (lane == 0) red[wave] = s;
    __syncthreads();
    float mu = (red[0] + red[1] + red[2] + red[3]) * (1.0f / Hh);
    float d2 = 0.f;
    #pragma unroll
    for (int i = 0; i < 8; ++i) { float dd = v[i] - mu; d2 += dd * dd; }
    #pragma unroll
    for (int d = 32; d >= 1; d >>= 1) d2 += __shfl_xor(d2, d);
    if (lane == 0) red[4 + wave] = d2;
    __syncthreads();
    float var = (red[4] + red[5] + red[6] + red[7]) * (1.0f / Hh);
    float rstd = rsqrtf(var + 1e-5f);
    s8v outv;
    #pragma unroll
    for (int i = 0; i < 8; ++i) {
        int c = tid * 8 + i;
        float ov = (v[i] - mu) * rstd * g[c] + be[c];
        outv[i] = (short)f2bf(ov);
    }
    *reinterpret_cast<s8v*>(y + base + tid * 8) = outv;
}

extern "C" void kernel_launch(void* const* d_in, const int* in_sizes, int n_in,
                              void* d_out, int out_size, void* d_ws, size_t ws_size,
                              hipStream_t stream) {
    const int*   tokens = (const int*)  d_in[0];
    const float* E    = (const float*)d_in[1];
    const float* Wi   = (const float*)d_in[2];
    const float* bi   = (const float*)d_in[3];
    const float* Wh   = (const float*)d_in[4];
    const float* Wo   = (const float*)d_in[5];
    const float* bo   = (const float*)d_in[6];
    const float* Wqkv = (const float*)d_in[7];
    const float* Wao  = (const float*)d_in[8];
    const float* bao  = (const float*)d_in[9];
    const float* lng  = (const float*)d_in[10];
    const float* lnb  = (const float*)d_in[11];
    const float* Wlm  = (const float*)d_in[12];
    const float* blm  = (const float*)d_in[13];
    float* out = (float*)d_out;

    char* ws = (char*)d_ws;
    size_t off = 0;
    auto alloc = [&](size_t bytes) -> void* {
        void* p = ws + off;
        off += (bytes + 255) & ~(size_t)255;
        return p;
    };
    unsigned short* bWi   = (unsigned short*)alloc((size_t)Hh * DE * 2);
    unsigned short* bWo   = (unsigned short*)alloc((size_t)Hh * Hh * 2);
    unsigned short* bWqkv = (unsigned short*)alloc((size_t)QKVC * Hh * 2);
    unsigned short* bWao  = (unsigned short*)alloc((size_t)Hh * Hh * 2);
    unsigned short* bWlm  = (unsigned short*)alloc((size_t)Vv * Hh * 2);
    unsigned short* xb    = (unsigned short*)alloc((size_t)Bb * Tt * DE * 2);
    float*          xi    = (float*)         alloc((size_t)Bb * Tt * Hh * 4);
    unsigned short* hsb   = (unsigned short*)alloc((size_t)Bb * Tt * Hh * 2);
    unsigned short* rnn   = (unsigned short*)alloc((size_t)Bb * Tt * Hh * 2);
    unsigned short* qkvb  = (unsigned short*)alloc((size_t)Bb * Tt * QKVC * 2);
    unsigned short* aob   = (unsigned short*)alloc((size_t)Bb * Tt * Hh * 2);
    unsigned short* aopb  = (unsigned short*)alloc((size_t)Bb * Tt * Hh * 2);
    unsigned short* yb    = (unsigned short*)alloc((size_t)Bb * Tt * Hh * 2);
    float*          hbuf  = (float*)         alloc((size_t)2 * 2 * Hh * 4);
    int*            flags = (int*)           alloc(NWG * 4);

    hipMemsetAsync(flags, 0, NWG * 4, stream);

    auto cvt = [&](const float* src, unsigned short* dst, size_t n) {
        int n4 = (int)(n / 4);
        k_cvt<<<(n4 + 255) / 256, 256, 0, stream>>>(src, dst, n4);
    };
    cvt(Wi,   bWi,   (size_t)Hh * DE);
    cvt(Wo,   bWo,   (size_t)Hh * Hh);
    cvt(Wqkv, bWqkv, (size_t)QKVC * Hh);
    cvt(Wao,  bWao,  (size_t)Hh * Hh);
    cvt(Wlm,  bWlm,  (size_t)Vv * Hh);

    k_embed<<<Bb * Tt, 256, 0, stream>>>(tokens, E, xb);

    // xi = x @ Wi^T + bi   (fp32 out)
    k_gemm<1, 1><<<dim3(Hh / 128, (Bb * Tt) / 128), 256, 0, stream>>>(xb, bWi, bi, xi, Bb * Tt, Hh, DE);
    // sequential RNN scan -> hs (bf16)
    k_scan<<<NWG, 512, 0, stream>>>(Wh, xi, hsb, hbuf, flags);
    // rnn_out = hs @ Wo^T + bo  (bf16)
    k_gemm<0, 1><<<dim3(Hh / 128, (Bb * Tt) / 128), 256, 0, stream>>>(hsb, bWo, bo, rnn, Bb * Tt, Hh, Hh);
    // qkv = rnn_out @ Wqkv^T    (bf16, no bias)
    k_gemm<0, 0><<<dim3(QKVC / 128, (Bb * Tt) / 128), 256, 0, stream>>>(rnn, bWqkv, nullptr, qkvb, Bb * Tt, QKVC, Hh);
    // causal attention
    k_attn<<<dim3(Tt / 64, Bb * NH), 256, 0, stream>>>(qkvb, aob);
    // ao @ Wao^T + bao          (bf16)
    k_gemm<0, 1><<<dim3(Hh / 128, (Bb * Tt) / 128), 256, 0, stream>>>(aob, bWao, bao, aopb, Bb * Tt, Hh, Hh);
    // y = LN(aop + rnn_out)
    k_ln<<<Bb * Tt, 256, 0, stream>>>(aopb, rnn, lng, lnb, yb);
    // logits = y @ Wlm^T + blm  (fp32 out)
    k_gemm<1, 1><<<dim3(Vv / 128, (Bb * Tt) / 128), 256, 0, stream>>>(yb, bWlm, blm, out, Bb * Tt, Vv, Hh);
}

// Round 2
// 8106.820 us; speedup vs baseline: 4.2054x; 4.2054x over previous
//
#include <hip/hip_runtime.h>
#include <stdint.h>

typedef __attribute__((ext_vector_type(4))) float f32x4;
typedef __attribute__((ext_vector_type(8))) short s8v;
typedef __attribute__((ext_vector_type(4))) unsigned short u4v;
typedef __bf16 bf16x8 __attribute__((ext_vector_type(8)));

#define DEV static __device__ __forceinline__

constexpr int Bb = 2, Tt = 2048, DE = 1024, Hh = 2048, NH = 16, KD = 128, VD = 128, Vv = 32000;
constexpr int QKVC = NH * (2 * KD + VD);   // 6144

DEV unsigned short f2bf(float x) {
    unsigned u = __builtin_bit_cast(unsigned, x);
    unsigned r = (u + 0x7fffu + ((u >> 16) & 1u)) >> 16;
    return (unsigned short)r;
}
DEV float bf2f(unsigned short b) {
    unsigned u = ((unsigned)b) << 16;
    return __builtin_bit_cast(float, u);
}
DEV bf16x8 as_bf(s8v v) { return __builtin_bit_cast(bf16x8, v); }

DEV void gll16(const void* g, void* l) {
    __builtin_amdgcn_global_load_lds((__attribute__((address_space(1))) void*)g,
                                     (__attribute__((address_space(3))) void*)l, 16, 0, 0);
}

// ---------------- fp32 -> bf16 convert ----------------
__global__ void k_cvt(const float* __restrict__ in, unsigned short* __restrict__ out, int n4) {
    int i = blockIdx.x * blockDim.x + threadIdx.x;
    if (i < n4) {
        float4 v = reinterpret_cast<const float4*>(in)[i];
        u4v o = {f2bf(v.x), f2bf(v.y), f2bf(v.z), f2bf(v.w)};
        reinterpret_cast<u4v*>(out)[i] = o;
    }
}

// ---------------- embedding gather + convert ----------------
__global__ void k_embed(const int* __restrict__ tok, const float* __restrict__ E,
                        unsigned short* __restrict__ x) {
    int bt = blockIdx.x;
    int t4 = threadIdx.x;   // 256 threads * 4 floats = 1024 = DE
    float4 v = reinterpret_cast<const float4*>(E + (size_t)tok[bt] * DE)[t4];
    u4v o = {f2bf(v.x), f2bf(v.y), f2bf(v.z), f2bf(v.w)};
    reinterpret_cast<u4v*>(x + (size_t)bt * DE)[t4] = o;
}

// ---------------- bf16 GEMM: C(MxN) = A(MxK) * Bw(NxK)^T + bias ----------------
template<int OUT_F32, int HAS_BIAS>
__global__ __launch_bounds__(256)
void k_gemm(const unsigned short* __restrict__ A, const unsigned short* __restrict__ Bw,
            const float* __restrict__ bias, void* __restrict__ Cv,
            int M, int N, int K) {
    __shared__ unsigned short As[128 * 32];
    __shared__ unsigned short Bs[128 * 32];
    const int tid = threadIdx.x;
    const int lane = tid & 63, wave = tid >> 6;
    const int wr = wave >> 1, wc = wave & 1;
    const int l15 = lane & 15, l16 = lane >> 4;
    const int m0 = blockIdx.y * 128, n0 = blockIdx.x * 128;

    f32x4 acc[4][4] = {};

    const int srow = tid >> 2, schunk = tid & 3;
    const unsigned short* gA = A + (size_t)(m0 + srow) * K + schunk * 8;
    const unsigned short* gB = Bw + (size_t)(n0 + srow) * K + schunk * 8;
    unsigned short* ldsA0 = As + wave * 512;
    unsigned short* ldsA1 = As + 2048 + wave * 512;
    unsigned short* ldsB0 = Bs + wave * 512;
    unsigned short* ldsB1 = Bs + 2048 + wave * 512;
    const size_t rs64 = (size_t)64 * K;

    for (int kt = 0; kt < K; kt += 32) {
        gll16(gA + kt, ldsA0);
        gll16(gA + rs64 + kt, ldsA1);
        gll16(gB + kt, ldsB0);
        gll16(gB + rs64 + kt, ldsB1);
        __syncthreads();
        s8v af[4], bfv[4];
        #pragma unroll
        for (int m = 0; m < 4; ++m)
            af[m] = *reinterpret_cast<const s8v*>(As + (wr * 64 + m * 16 + l15) * 32 + l16 * 8);
        #pragma unroll
        for (int n = 0; n < 4; ++n)
            bfv[n] = *reinterpret_cast<const s8v*>(Bs + (wc * 64 + n * 16 + l15) * 32 + l16 * 8);
        #pragma unroll
        for (int m = 0; m < 4; ++m)
            #pragma unroll
            for (int n = 0; n < 4; ++n)
                acc[m][n] = __builtin_amdgcn_mfma_f32_16x16x32_bf16(as_bf(af[m]), as_bf(bfv[n]), acc[m][n], 0, 0, 0);
        __syncthreads();
    }

    #pragma unroll
    for (int m = 0; m < 4; ++m) {
        const int r0 = m0 + wr * 64 + m * 16 + l16 * 4;
        #pragma unroll
        for (int n = 0; n < 4; ++n) {
            const int c = n0 + wc * 64 + n * 16 + l15;
            const float bv = HAS_BIAS ? bias[c] : 0.0f;
            #pragma unroll
            for (int j = 0; j < 4; ++j) {
                float v = acc[m][n][j] + bv;
                if (OUT_F32) ((float*)Cv)[(size_t)(r0 + j) * N + c] = v;
                else ((unsigned short*)Cv)[(size_t)(r0 + j) * N + c] = f2bf(v);
            }
        }
    }
}

// ---------------- persistent RNN scan (fence-free sentinel data-flow) ----------------
// h_t = gelu(xi_t + Wh h_{t-1})
// 128 WGs x 512 thr: wg>>6 selects batch chain, wg&63 selects a 32-col slice.
// Per thread: 2 columns x 64 k (k-interleaved), weights in 32 float4 VGPRs.
// Cross-WG h broadcast via write-once hseq[t][b][col] fp32 buffer, poisoned to
// 0xFFFFFFFF per launch; relaxed agent-scope atomics only (no fences, no L2 wb/inv).
__global__ __launch_bounds__(512, 2)
void k_scan(const float* __restrict__ Wh, const float* __restrict__ xi,
            unsigned short* __restrict__ hs, float* __restrict__ hseq) {
    const int wg = blockIdx.x;
    const int tid = threadIdx.x;
    const int bsel = wg >> 6;           // batch chain
    const int g = tid >> 5;             // 0..15 column pair group
    const int kp = tid & 31;            // k partition
    const int col0 = (wg & 63) * 32 + g * 2;

    __shared__ float hsh[Hh];           // h_{t-1} for this batch, fp32, 8KB

    // weights: w0/w1[i] = Wh[col][kp*4 + i*128 .. +4]
    f32x4 w0[16], w1[16];
    const float* wr0 = Wh + (size_t)col0 * Hh;
    const float* wr1 = Wh + (size_t)(col0 + 1) * Hh;
    #pragma unroll
    for (int i = 0; i < 16; ++i) {
        w0[i] = *reinterpret_cast<const f32x4*>(wr0 + kp * 4 + i * 128);
        w1[i] = *reinterpret_cast<const f32x4*>(wr1 + kp * 4 + i * 128);
    }
    for (int i = tid; i < Hh; i += 512) hsh[i] = 0.0f;
    __syncthreads();

    for (int t = 0; t < Tt; ++t) {
        float sa = 0.f, sb = 0.f;
        #pragma unroll
        for (int i = 0; i < 16; ++i) {
            const f32x4 h = *reinterpret_cast<const f32x4*>(&hsh[kp * 4 + i * 128]);
            sa += w0[i][0]*h[0] + w0[i][1]*h[1] + w0[i][2]*h[2] + w0[i][3]*h[3];
            sb += w1[i][0]*h[0] + w1[i][1]*h[1] + w1[i][2]*h[2] + w1[i][3]*h[3];
        }
        #pragma unroll
        for (int d = 16; d >= 1; d >>= 1) {
            sa += __shfl_xor(sa, d);
            sb += __shfl_xor(sb, d);
        }
        if (kp == 0) {
            const size_t xrow = ((size_t)bsel * Tt + t) * Hh;
            float xa = xi[xrow + col0];
            float xb_ = xi[xrow + col0 + 1];
            float aa = xa + sa, ab = xb_ + sb;
            float ha = 0.5f * aa * (1.0f + erff(aa * 0.70710678118654752f));
            float hb = 0.5f * ab * (1.0f + erff(ab * 0.70710678118654752f));
            float* dst = hseq + ((size_t)t * 2 + bsel) * Hh;
            __hip_atomic_store(dst + col0,     ha, __ATOMIC_RELAXED, __HIP_MEMORY_SCOPE_AGENT);
            __hip_atomic_store(dst + col0 + 1, hb, __ATOMIC_RELAXED, __HIP_MEMORY_SCOPE_AGENT);
            hs[xrow + col0]     = f2bf(ha);
            hs[xrow + col0 + 1] = f2bf(hb);
        }
        __syncthreads();   // everyone done reading hsh for step t
        if (t + 1 < Tt) {
            // poll-load h_t (the load IS the synchronization)
            const unsigned long long* src =
                reinterpret_cast<const unsigned long long*>(hseq + ((size_t)t * 2 + bsel) * Hh);
            unsigned long long v0 = 0, v1 = 0;
            bool n0 = true, n1 = true;
            int spins = 0;
            for (;;) {
                if (n0) {
                    v0 = __hip_atomic_load(src + tid, __ATOMIC_RELAXED, __HIP_MEMORY_SCOPE_AGENT);
                    n0 = ((unsigned)v0 == 0xFFFFFFFFu) || ((unsigned)(v0 >> 32) == 0xFFFFFFFFu);
                }
                if (n1) {
                    v1 = __hip_atomic_load(src + 512 + tid, __ATOMIC_RELAXED, __HIP_MEMORY_SCOPE_AGENT);
                    n1 = ((unsigned)v1 == 0xFFFFFFFFu) || ((unsigned)(v1 >> 32) == 0xFFFFFFFFu);
                }
                if (!(n0 || n1)) break;
                if (++spins > (1 << 24)) break;   // anti-hang insurance
            }
            reinterpret_cast<unsigned long long*>(hsh)[tid]       = v0;
            reinterpret_cast<unsigned long long*>(hsh)[tid + 512] = v1;
            __syncthreads();
        }
    }
}

// ---------------- causal flash attention ----------------
__global__ __launch_bounds__(256)
void k_attn(const unsigned short* __restrict__ qkv, unsigned short* __restrict__ ao) {
    const int tid = threadIdx.x;
    const int lane = tid & 63, wave = tid >> 6;
    const int l15 = lane & 15, l16 = lane >> 4;
    const int qt = blockIdx.x, bh = blockIdx.y;
    const int b = bh >> 4, hh = bh & 15;

    __shared__ unsigned short Ks[64][136];
    __shared__ unsigned short Vt[128][72];
    __shared__ unsigned short Ps[4][16][72];

    const int qr0 = qt * 64 + wave * 16;
    const unsigned short* qbase = qkv + (size_t)(b * Tt + qr0 + l15) * QKVC + hh * KD;
    s8v qf[4];
    #pragma unroll
    for (int kc = 0; kc < 4; ++kc)
        qf[kc] = *reinterpret_cast<const s8v*>(qbase + kc * 32 + l16 * 8);

    f32x4 o[8] = {};
    float mrow[4] = {-3e38f, -3e38f, -3e38f, -3e38f};
    float lrow[4] = {0.f, 0.f, 0.f, 0.f};

    const int kvend = qt * 64 + 64;
    for (int kv0 = 0; kv0 < kvend; kv0 += 64) {
        __syncthreads();
        {
            const int r = tid >> 4, c = tid & 15;
            #pragma unroll
            for (int p = 0; p < 4; ++p) {
                int row = r + p * 16;
                const unsigned short* src = qkv + (size_t)(b * Tt + kv0 + row) * QKVC + hh * KD;
                s8v kv8 = *reinterpret_cast<const s8v*>(src + NH * KD + c * 8);
                *reinterpret_cast<s8v*>(&Ks[row][c * 8]) = kv8;
                s8v vv8 = *reinterpret_cast<const s8v*>(src + 2 * NH * KD + c * 8);
                #pragma unroll
                for (int i = 0; i < 8; ++i)
                    Vt[c * 8 + i][row] = (unsigned short)vv8[i];
            }
        }
        __syncthreads();
        f32x4 s[4] = {};
        #pragma unroll
        for (int kc = 0; kc < 4; ++kc) {
            #pragma unroll
            for (int nf = 0; nf < 4; ++nf) {
                s8v kf = *reinterpret_cast<const s8v*>(&Ks[nf * 16 + l15][kc * 32 + l16 * 8]);
                s[nf] = __builtin_amdgcn_mfma_f32_16x16x32_bf16(as_bf(qf[kc]), as_bf(kf), s[nf], 0, 0, 0);
            }
        }
        const float sc = 0.088388347648318447f;   // 1/sqrt(128)
        #pragma unroll
        for (int nf = 0; nf < 4; ++nf)
            #pragma unroll
            for (int jj = 0; jj < 4; ++jj) {
                int col = kv0 + nf * 16 + l15;
                int row = qr0 + l16 * 4 + jj;
                s[nf][jj] = (col <= row) ? s[nf][jj] * sc : -3e38f;
            }
        #pragma unroll
        for (int jj = 0; jj < 4; ++jj) {
            float vm = fmaxf(fmaxf(s[0][jj], s[1][jj]), fmaxf(s[2][jj], s[3][jj]));
            vm = fmaxf(vm, __shfl_xor(vm, 1));
            vm = fmaxf(vm, __shfl_xor(vm, 2));
            vm = fmaxf(vm, __shfl_xor(vm, 4));
            vm = fmaxf(vm, __shfl_xor(vm, 8));
            float mn = fmaxf(mrow[jj], vm);
            float scale = __expf(mrow[jj] - mn);
            float ps = 0.f;
            #pragma unroll
            for (int nf = 0; nf < 4; ++nf) {
                float p = __expf(s[nf][jj] - mn);
                s[nf][jj] = p;
                ps += p;
            }
            ps += __shfl_xor(ps, 1); ps += __shfl_xor(ps, 2);
            ps += __shfl_xor(ps, 4); ps += __shfl_xor(ps, 8);
            lrow[jj] = lrow[jj] * scale + ps;
            mrow[jj] = mn;
            #pragma unroll
            for (int nf = 0; nf < 8; ++nf) o[nf][jj] *= scale;
        }
        #pragma unroll
        for (int nf = 0; nf < 4; ++nf)
            #pragma unroll
            for (int jj = 0; jj < 4; ++jj)
                Ps[wave][l16 * 4 + jj][nf * 16 + l15] = f2bf(s[nf][jj]);
        __syncthreads();
        #pragma unroll
        for (int kc = 0; kc < 2; ++kc) {
            s8v pf = *reinterpret_cast<const s8v*>(&Ps[wave][l15][kc * 32 + l16 * 8]);
            #pragma unroll
            for (int nf = 0; nf < 8; ++nf) {
                s8v vf = *reinterpret_cast<const s8v*>(&Vt[nf * 16 + l15][kc * 32 + l16 * 8]);
                o[nf] = __builtin_amdgcn_mfma_f32_16x16x32_bf16(as_bf(pf), as_bf(vf), o[nf], 0, 0, 0);
            }
        }
    }
    #pragma unroll
    for (int nf = 0; nf < 8; ++nf)
        #pragma unroll
        for (int jj = 0; jj < 4; ++jj) {
            float v = o[nf][jj] / lrow[jj];
            ao[(size_t)(b * Tt + qr0 + l16 * 4 + jj) * Hh + hh * VD + nf * 16 + l15] = f2bf(v);
        }
}

// ---------------- residual + LayerNorm ----------------
__global__ __launch_bounds__(256)
void k_ln(const unsigned short* __restrict__ aop, const unsigned short* __restrict__ rnn,
          const float* __restrict__ g, const float* __restrict__ be,
          unsigned short* __restrict__ y) {
    const int row = blockIdx.x, tid = threadIdx.x;
    const int lane = tid & 63, wave = tid >> 6;
    const size_t base = (size_t)row * Hh;
    s8v a8 = *reinterpret_cast<const s8v*>(aop + base + tid * 8);
    s8v r8 = *reinterpret_cast<const s8v*>(rnn + base + tid * 8);
    float v[8]; float s = 0.f;
    #pragma unroll
    for (int i = 0; i < 8; ++i) {
        v[i] = bf2f((unsigned short)a8[i]) + bf2f((unsigned short)r8[i]);
        s += v[i];
    }
    #pragma unroll
    for (int d = 32; d >= 1; d >>= 1) s += __shfl_xor(s, d);
    __shared__ float red[8];
    if (lane == 0) red[wave] = s;
    __syncthreads();
    float mu = (red[0] + red[1] + red[2] + red[3]) * (1.0f / Hh);
    float d2 = 0.f;
    #pragma unroll
    for (int i = 0; i < 8; ++i) { float dd = v[i] - mu; d2 += dd * dd; }
    #pragma unroll
    for (int d = 32; d >= 1; d >>= 1) d2 += __shfl_xor(d2, d);
    if (lane == 0) red[4 + wave] = d2;
    __syncthreads();
    float var = (red[4] + red[5] + red[6] + red[7]) * (1.0f / Hh);
    float rstd = rsqrtf(var + 1e-5f);
    s8v outv;
    #pragma unroll
    for (int i = 0; i < 8; ++i) {
        int c = tid * 8 + i;
        float ov = (v[i] - mu) * rstd * g[c] + be[c];
        outv[i] = (short)f2bf(ov);
    }
    *reinterpret_cast<s8v*>(y + base + tid * 8) = outv;
}

extern "C" void kernel_launch(void* const* d_in, const int* in_sizes, int n_in,
                              void* d_out, int out_size, void* d_ws, size_t ws_size,
                              hipStream_t stream) {
    const int*   tokens = (const int*)  d_in[0];
    const float* E    = (const float*)d_in[1];
    const float* Wi   = (const float*)d_in[2];
    const float* bi   = (const float*)d_in[3];
    const float* Wh   = (const float*)d_in[4];
    const float* Wo   = (const float*)d_in[5];
    const float* bo   = (const float*)d_in[6];
    const float* Wqkv = (const float*)d_in[7];
    const float* Wao  = (const float*)d_in[8];
    const float* bao  = (const float*)d_in[9];
    const float* lng  = (const float*)d_in[10];
    const float* lnb  = (const float*)d_in[11];
    const float* Wlm  = (const float*)d_in[12];
    const float* blm  = (const float*)d_in[13];
    float* out = (float*)d_out;

    char* ws = (char*)d_ws;
    size_t off = 0;
    auto alloc = [&](size_t bytes) -> void* {
        void* p = ws + off;
        off += (bytes + 255) & ~(size_t)255;
        return p;
    };
    unsigned short* bWi   = (unsigned short*)alloc((size_t)Hh * DE * 2);
    unsigned short* bWo   = (unsigned short*)alloc((size_t)Hh * Hh * 2);
    unsigned short* bWqkv = (unsigned short*)alloc((size_t)QKVC * Hh * 2);
    unsigned short* bWao  = (unsigned short*)alloc((size_t)Hh * Hh * 2);
    unsigned short* bWlm  = (unsigned short*)alloc((size_t)Vv * Hh * 2);
    unsigned short* xb    = (unsigned short*)alloc((size_t)Bb * Tt * DE * 2);
    float*          xi    = (float*)         alloc((size_t)Bb * Tt * Hh * 4);
    unsigned short* hsb   = (unsigned short*)alloc((size_t)Bb * Tt * Hh * 2);
    unsigned short* rnn   = (unsigned short*)alloc((size_t)Bb * Tt * Hh * 2);
    unsigned short* qkvb  = (unsigned short*)alloc((size_t)Bb * Tt * QKVC * 2);
    unsigned short* aob   = (unsigned short*)alloc((size_t)Bb * Tt * Hh * 2);
    unsigned short* aopb  = (unsigned short*)alloc((size_t)Bb * Tt * Hh * 2);
    unsigned short* yb    = (unsigned short*)alloc((size_t)Bb * Tt * Hh * 2);

    // hseq (32MB, write-once per step) aliases qkvb's space: qkvb (50MB) is
    // only written by the qkv GEMM, which runs strictly after k_scan completes.
    float* hseq = (float*)qkvb;
    hipMemsetAsync(hseq, 0xFF, (size_t)Tt * 2 * Hh * 4, stream);   // sentinel poison

    auto cvt = [&](const float* src, unsigned short* dst, size_t n) {
        int n4 = (int)(n / 4);
        k_cvt<<<(n4 + 255) / 256, 256, 0, stream>>>(src, dst, n4);
    };
    cvt(Wi,   bWi,   (size_t)Hh * DE);
    cvt(Wo,   bWo,   (size_t)Hh * Hh);
    cvt(Wqkv, bWqkv, (size_t)QKVC * Hh);
    cvt(Wao,  bWao,  (size_t)Hh * Hh);
    cvt(Wlm,  bWlm,  (size_t)Vv * Hh);

    k_embed<<<Bb * Tt, 256, 0, stream>>>(tokens, E, xb);

    // xi = x @ Wi^T + bi   (fp32 out)
    k_gemm<1, 1><<<dim3(Hh / 128, (Bb * Tt) / 128), 256, 0, stream>>>(xb, bWi, bi, xi, Bb * Tt, Hh, DE);
    // sequential RNN scan -> hs (bf16)
    k_scan<<<128, 512, 0, stream>>>(Wh, xi, hsb, hseq);
    // rnn_out = hs @ Wo^T + bo  (bf16)
    k_gemm<0, 1><<<dim3(Hh / 128, (Bb * Tt) / 128), 256, 0, stream>>>(hsb, bWo, bo, rnn, Bb * Tt, Hh, Hh);
    // qkv = rnn_out @ Wqkv^T    (bf16, no bias)
    k_gemm<0, 0><<<dim3(QKVC / 128, (Bb * Tt) / 128), 256, 0, stream>>>(rnn, bWqkv, nullptr, qkvb, Bb * Tt, QKVC, Hh);
    // causal attention
    k_attn<<<dim3(Tt / 64, Bb * NH), 256, 0, stream>>>(qkvb, aob);
    // ao @ Wao^T + bao          (bf16)
    k_gemm<0, 1><<<dim3(Hh / 128, (Bb * Tt) / 128), 256, 0, stream>>>(aob, bWao, bao, aopb, Bb * Tt, Hh, Hh);
    // y = LN(aop + rnn_out)
    k_ln<<<Bb * Tt, 256, 0, stream>>>(aopb, rnn, lng, lnb, yb);
    // logits = y @ Wlm^T + blm  (fp32 out)
    k_gemm<1, 1><<<dim3(Vv / 128, (Bb * Tt) / 128), 256, 0, stream>>>(yb, bWlm, blm, out, Bb * Tt, Vv, Hh);
}